// Round 1
// baseline (84.429 us; speedup 1.0000x reference)
//
#include <hip/hip_runtime.h>

// Problem constants (from setup_inputs): N=32, D=32, S=32, B=15, m=128
#define N_ 32
#define D_ 32
#define S_ 32
#define M_ 128
#define INV_M (1.0f / 128.0f)
#define INV_M2 (1.0f / (128.0f * 128.0f))

// Workspace layout (float offsets). Total ~790,528 floats = ~3.02 MiB.
#define WS_ROWSUM  0         // [N*D][128]
#define WS_COLSUM  131072    // [N*D][128]
#define WS_DIAG    262144    // [N*D][128]
#define WS_SUMDIAG 393216    // [N*D]
#define WS_TOT     394240    // [N*D]
#define WS_RV      395264    // [N*S][128]  (includes K + bias)
#define WS_CV      526336    // [N*S][128]
#define WS_DG      657408    // [N*S][128]  (includes diag_bias)
#define WS_WPACK   788480    // float2 [D][S] = (c_op10, c_op11)

// ---------------- Kernel A: per-(n,d) reductions ----------------
__global__ __launch_bounds__(256) void eq2_reduce(const float* __restrict__ x,
                                                  float* __restrict__ ws) {
    int nd = blockIdx.x;              // n*D + d
    int t  = threadIdx.x;
    int g  = t >> 5;                  // row group 0..7 (16 rows each)
    int j4 = t & 31;                  // float4 column group (cols 4*j4..4*j4+3)

    const float4* xp = (const float4*)(x + (size_t)nd * (M_ * M_));

    float* rowsum  = ws + WS_ROWSUM;
    float* colsum  = ws + WS_COLSUM;
    float* diag    = ws + WS_DIAG;
    float* sumdiag = ws + WS_SUMDIAG;
    float* tot     = ws + WS_TOT;

    float4 cs = {0.f, 0.f, 0.f, 0.f};
    float dsum = 0.f, ttot = 0.f;

    for (int r = 0; r < 16; ++r) {
        int i = g * 16 + r;
        float4 v = xp[i * 32 + j4];
        cs.x += v.x; cs.y += v.y; cs.z += v.z; cs.w += v.w;
        float rp = v.x + v.y + v.z + v.w;
        ttot += rp;
        int c = i - 4 * j4;           // diagonal element if 0..3
        if (c >= 0 && c < 4) {
            float dv = (c == 0) ? v.x : (c == 1) ? v.y : (c == 2) ? v.z : v.w;
            diag[nd * M_ + i] = dv;
            dsum += dv;
        }
        // row sum: reduce over the 32 lanes covering this row
        float rs = rp;
        for (int msk = 1; msk < 32; msk <<= 1) rs += __shfl_xor(rs, msk, 64);
        if ((t & 31) == 0) rowsum[nd * M_ + i] = rs;
    }

    __shared__ float4 cs_lds[8][32];
    __shared__ float  red[2][4];
    cs_lds[g][j4] = cs;

    // block-reduce dsum / ttot (full 64-lane wave, then across 4 waves)
    for (int msk = 1; msk < 64; msk <<= 1) {
        dsum += __shfl_xor(dsum, msk, 64);
        ttot += __shfl_xor(ttot, msk, 64);
    }
    int wave = t >> 6, lane = t & 63;
    if (lane == 0) { red[0][wave] = dsum; red[1][wave] = ttot; }
    __syncthreads();

    if (t < 32) {
        float4 a = cs_lds[0][t];
        for (int gg = 1; gg < 8; ++gg) {
            float4 b = cs_lds[gg][t];
            a.x += b.x; a.y += b.y; a.z += b.z; a.w += b.w;
        }
        ((float4*)(colsum + nd * M_))[t] = a;
    }
    if (t == 0) {
        sumdiag[nd] = red[0][0] + red[0][1] + red[0][2] + red[0][3];
        tot[nd]     = red[1][0] + red[1][1] + red[1][2] + red[1][3];
    }
}

// ---------------- Kernel B: contract reductions with coefs over d ----------------
// coefs layout: [d][s][b], b in 0..14 -> op1..op15
__global__ __launch_bounds__(128) void eq2_combine(const float* __restrict__ coefs,
                                                   const float* __restrict__ bias,
                                                   const float* __restrict__ diag_bias,
                                                   float* __restrict__ ws) {
    int b = blockIdx.x;
    int n = b >> 5, s = b & 31;
    int i = threadIdx.x;              // 0..127

    const float* rowsum  = ws + WS_ROWSUM;
    const float* colsum  = ws + WS_COLSUM;
    const float* diag    = ws + WS_DIAG;
    const float* sumdiag = ws + WS_SUMDIAG;
    const float* tot     = ws + WS_TOT;

    float rv = 0.f, cv = 0.f, dg = 0.f, kk = 0.f;
    for (int d = 0; d < D_; ++d) {
        const float* cf = coefs + (d * S_ + s) * 15;   // uniform -> s_load
        float rs = rowsum[(n * D_ + d) * M_ + i];
        float c2 = colsum[(n * D_ + d) * M_ + i];
        float dv = diag[(n * D_ + d) * M_ + i];
        float sd = sumdiag[n * D_ + d];
        float tt = tot[n * D_ + d];
        rv += (cf[5] * c2 + cf[6] * rs) * INV_M + cf[11] * dv;          // op6,7,12
        cv += (cf[7] * c2 + cf[8] * rs) * INV_M + cf[12] * dv;          // op8,9,13
        dg += cf[0] * dv + (cf[1] * sd + cf[2] * rs + cf[3] * c2) * INV_M
              + cf[4] * tt * INV_M2;                                    // op1..5
        kk += cf[13] * sd * INV_M + cf[14] * tt * INV_M2;               // op14,15
    }
    ws[WS_RV + (n * S_ + s) * M_ + i] = rv + kk + bias[s];
    ws[WS_CV + (n * S_ + s) * M_ + i] = cv;
    ws[WS_DG + (n * S_ + s) * M_ + i] = dg + diag_bias[s];

    // pack (c10, c11) once (blocks with n==0)
    if (n == 0 && i < D_) {
        const float* cf = coefs + (i * S_ + s) * 15;
        float2* wpack = (float2*)(ws + WS_WPACK);
        wpack[i * S_ + s] = make_float2(cf[9], cf[10]);
    }
}

// ---------------- Kernel C: dense part + epilogue ----------------
// Block: 256 threads -> output tile 16 rows (r0..r0+15) x 32 cols (c0..c0+31), all 32 s.
__global__ __launch_bounds__(256) void eq2_main(const float* __restrict__ x,
                                                const float* __restrict__ ws,
                                                float* __restrict__ out) {
    int n  = blockIdx.z;
    int r0 = blockIdx.y * 16;
    int c0 = blockIdx.x * 32;
    int t  = threadIdx.x;
    int jj = t & 31;                  // col in tile
    int ii = t >> 5;                  // 0..7; rows ii and ii+8

    const float*  Rv    = ws + WS_RV;
    const float*  Cv    = ws + WS_CV;
    const float*  Dg    = ws + WS_DG;
    const float2* wpack = (const float2*)(ws + WS_WPACK);

    __shared__ float Bl[2][32][18];   // transposed-source tile, padded stride 18

    float acc0[S_], acc1[S_];
#pragma unroll
    for (int s = 0; s < S_; ++s) { acc0[s] = 0.f; acc1[s] = 0.f; }

    const float* xn = x + (size_t)n * D_ * M_ * M_;
    int jr = t >> 3;                  // 0..31
    int cc = (t & 7) * 2;             // 0,2,...,14

    // stage d=0: B tile rows c0..c0+31, cols r0..r0+15
    {
        float2 v = *(const float2*)(xn + (c0 + jr) * M_ + r0 + cc);
        *(float2*)&Bl[0][jr][cc] = v;
    }

    int gi0 = r0 + ii, gi1 = gi0 + 8, gj = c0 + jj;

    for (int d = 0; d < D_; ++d) {
        __syncthreads();              // buf[d&1] ready; prev reads of buf[(d+1)&1] done
        if (d + 1 < D_) {
            float2 v = *(const float2*)(xn + (size_t)(d + 1) * M_ * M_ + (c0 + jr) * M_ + r0 + cc);
            *(float2*)&Bl[(d + 1) & 1][jr][cc] = v;
        }
        float xv0 = xn[(size_t)d * M_ * M_ + gi0 * M_ + gj];
        float xv1 = xn[(size_t)d * M_ * M_ + gi1 * M_ + gj];
        float xt0 = Bl[d & 1][jj][ii];
        float xt1 = Bl[d & 1][jj][ii + 8];
        const float2* wd = wpack + d * S_;    // uniform -> s_load
#pragma unroll
        for (int s = 0; s < S_; ++s) {
            float2 cw = wd[s];
            acc0[s] = fmaf(cw.x, xv0, fmaf(cw.y, xt0, acc0[s]));
            acc1[s] = fmaf(cw.x, xv1, fmaf(cw.y, xt1, acc1[s]));
        }
    }

    // epilogue: rank-1 terms + diagonal term + store
#pragma unroll
    for (int s = 0; s < S_; ++s) {
        int base = (n * S_ + s) * M_;
        float a0 = acc0[s] + Rv[base + gi0];
        float a1 = acc1[s] + Rv[base + gi1];
        float cvv = Cv[base + gj];
        a0 += cvv; a1 += cvv;
        if (gi0 == gj) a0 += Dg[base + gi0];
        if (gi1 == gj) a1 += Dg[base + gi1];
        out[(size_t)base * M_ + gi0 * M_ + gj] = a0;
        out[(size_t)base * M_ + gi1 * M_ + gj] = a1;
    }
}

extern "C" void kernel_launch(void* const* d_in, const int* in_sizes, int n_in,
                              void* d_out, int out_size, void* d_ws, size_t ws_size,
                              hipStream_t stream) {
    const float* x         = (const float*)d_in[0];
    const float* coefs     = (const float*)d_in[1];
    const float* bias      = (const float*)d_in[2];
    const float* diag_bias = (const float*)d_in[3];
    float* out = (float*)d_out;
    float* ws  = (float*)d_ws;   // needs ~3.1 MiB

    hipLaunchKernelGGL(eq2_reduce,  dim3(N_ * D_), dim3(256), 0, stream, x, ws);
    hipLaunchKernelGGL(eq2_combine, dim3(N_ * S_), dim3(128), 0, stream, coefs, bias, diag_bias, ws);
    hipLaunchKernelGGL(eq2_main,    dim3(4, 8, N_), dim3(256), 0, stream, x, ws, out);
}

// Round 2
// 76.304 us; speedup vs baseline: 1.1065x; 1.1065x over previous
//
#include <hip/hip_runtime.h>

// Problem constants (from setup_inputs): N=32, D=32, S=32, B=15, m=128
#define N_ 32
#define D_ 32
#define S_ 32
#define M_ 128
#define INV_M (1.0f / 128.0f)
#define INV_M2 (1.0f / (128.0f * 128.0f))

// Workspace layout (float offsets). Total ~790,528 floats = ~3.02 MiB.
#define WS_ROWSUM  0         // [N*D][128]
#define WS_COLSUM  131072    // [N*D][128]
#define WS_DIAG    262144    // [N*D][128]
#define WS_SUMDIAG 393216    // [N*D]
#define WS_TOT     394240    // [N*D]
#define WS_RV      395264    // [N*S][128]  (includes K + bias)
#define WS_CV      526336    // [N*S][128]
#define WS_DG      657408    // [N*S][128]  (includes diag_bias)
#define WS_WPACK   788480    // float2 [D][S] = (c_op10, c_op11)

// ---------------- Kernel A: per-(n,d) reductions ----------------
__global__ __launch_bounds__(256) void eq2_reduce(const float* __restrict__ x,
                                                  float* __restrict__ ws) {
    int nd = blockIdx.x;              // n*D + d
    int t  = threadIdx.x;
    int g  = t >> 5;                  // row group 0..7 (16 rows each)
    int j4 = t & 31;                  // float4 column group (cols 4*j4..4*j4+3)

    const float4* xp = (const float4*)(x + (size_t)nd * (M_ * M_));

    float* rowsum  = ws + WS_ROWSUM;
    float* colsum  = ws + WS_COLSUM;
    float* diag    = ws + WS_DIAG;
    float* sumdiag = ws + WS_SUMDIAG;
    float* tot     = ws + WS_TOT;

    float4 cs = {0.f, 0.f, 0.f, 0.f};
    float dsum = 0.f, ttot = 0.f;

    for (int r = 0; r < 16; ++r) {
        int i = g * 16 + r;
        float4 v = xp[i * 32 + j4];
        cs.x += v.x; cs.y += v.y; cs.z += v.z; cs.w += v.w;
        float rp = v.x + v.y + v.z + v.w;
        ttot += rp;
        int c = i - 4 * j4;           // diagonal element if 0..3
        if (c >= 0 && c < 4) {
            float dv = (c == 0) ? v.x : (c == 1) ? v.y : (c == 2) ? v.z : v.w;
            diag[nd * M_ + i] = dv;
            dsum += dv;
        }
        // row sum: reduce over the 32 lanes covering this row
        float rs = rp;
        for (int msk = 1; msk < 32; msk <<= 1) rs += __shfl_xor(rs, msk, 64);
        if ((t & 31) == 0) rowsum[nd * M_ + i] = rs;
    }

    __shared__ float4 cs_lds[8][32];
    __shared__ float  red[2][4];
    cs_lds[g][j4] = cs;

    // block-reduce dsum / ttot (full 64-lane wave, then across 4 waves)
    for (int msk = 1; msk < 64; msk <<= 1) {
        dsum += __shfl_xor(dsum, msk, 64);
        ttot += __shfl_xor(ttot, msk, 64);
    }
    int wave = t >> 6, lane = t & 63;
    if (lane == 0) { red[0][wave] = dsum; red[1][wave] = ttot; }
    __syncthreads();

    if (t < 32) {
        float4 a = cs_lds[0][t];
        for (int gg = 1; gg < 8; ++gg) {
            float4 b = cs_lds[gg][t];
            a.x += b.x; a.y += b.y; a.z += b.z; a.w += b.w;
        }
        ((float4*)(colsum + nd * M_))[t] = a;
    }
    if (t == 0) {
        sumdiag[nd] = red[0][0] + red[0][1] + red[0][2] + red[0][3];
        tot[nd]     = red[1][0] + red[1][1] + red[1][2] + red[1][3];
    }
}

// ---------------- Kernel B: contract reductions with coefs over d ----------------
// coefs layout: [d][s][b], b in 0..14 -> op1..op15
__global__ __launch_bounds__(128) void eq2_combine(const float* __restrict__ coefs,
                                                   const float* __restrict__ bias,
                                                   const float* __restrict__ diag_bias,
                                                   float* __restrict__ ws) {
    int b = blockIdx.x;
    int n = b >> 5, s = b & 31;
    int i = threadIdx.x;              // 0..127

    const float* rowsum  = ws + WS_ROWSUM;
    const float* colsum  = ws + WS_COLSUM;
    const float* diag    = ws + WS_DIAG;
    const float* sumdiag = ws + WS_SUMDIAG;
    const float* tot     = ws + WS_TOT;

    float rv = 0.f, cv = 0.f, dg = 0.f, kk = 0.f;
    for (int d = 0; d < D_; ++d) {
        const float* cf = coefs + (d * S_ + s) * 15;   // uniform -> s_load
        float rs = rowsum[(n * D_ + d) * M_ + i];
        float c2 = colsum[(n * D_ + d) * M_ + i];
        float dv = diag[(n * D_ + d) * M_ + i];
        float sd = sumdiag[n * D_ + d];
        float tt = tot[n * D_ + d];
        rv += (cf[5] * c2 + cf[6] * rs) * INV_M + cf[11] * dv;          // op6,7,12
        cv += (cf[7] * c2 + cf[8] * rs) * INV_M + cf[12] * dv;          // op8,9,13
        dg += cf[0] * dv + (cf[1] * sd + cf[2] * rs + cf[3] * c2) * INV_M
              + cf[4] * tt * INV_M2;                                    // op1..5
        kk += cf[13] * sd * INV_M + cf[14] * tt * INV_M2;               // op14,15
    }
    ws[WS_RV + (n * S_ + s) * M_ + i] = rv + kk + bias[s];
    ws[WS_CV + (n * S_ + s) * M_ + i] = cv;
    ws[WS_DG + (n * S_ + s) * M_ + i] = dg + diag_bias[s];

    // pack (c10, c11) once (blocks with n==0)
    if (n == 0 && i < D_) {
        const float* cf = coefs + (i * S_ + s) * 15;
        float2* wpack = (float2*)(ws + WS_WPACK);
        wpack[i * S_ + s] = make_float2(cf[9], cf[10]);
    }
}

// ---------------- Kernel C: dense part + epilogue ----------------
// 1024 blocks (1D, XCD-swizzled so all 32 tile-blocks of one n share an XCD's L2).
// Block: 256 threads -> output tile 16 rows x 32 cols, all 32 s.
// Software-pipelined: direct loads prefetched 1 d ahead, staged loads 2 d ahead.
__global__ __launch_bounds__(256) void eq2_main(const float* __restrict__ x,
                                                const float* __restrict__ ws,
                                                float* __restrict__ out) {
    // XCD-chunked swizzle (assumes round-robin blockIdx -> XCD):
    // n = (lid&7) + 8*(lid>>8); tile = (lid>>3)&31.  Bijective over 1024 blocks.
    int lid  = blockIdx.x;
    int n    = (lid & 7) + ((lid >> 8) << 3);
    int tile = (lid >> 3) & 31;
    int r0 = (tile >> 2) * 16;        // row tile (8 of them)
    int c0 = (tile & 3) * 32;         // col tile (4 of them)

    int t  = threadIdx.x;
    int jj = t & 31;                  // col in tile
    int ii = t >> 5;                  // 0..7; rows ii and ii+8

    const float*  Rv    = ws + WS_RV;
    const float*  Cv    = ws + WS_CV;
    const float*  Dg    = ws + WS_DG;
    const float2* wpack = (const float2*)(ws + WS_WPACK);

    __shared__ float Bl[2][32][18];   // transposed-source tile, padded stride 18

    float acc0[S_], acc1[S_];
#pragma unroll
    for (int s = 0; s < S_; ++s) { acc0[s] = 0.f; acc1[s] = 0.f; }

    const float* xn = x + (size_t)n * D_ * M_ * M_;
    int jr = t >> 3;                  // 0..31  (staged tile row = source row c0+jr)
    int cc = (t & 7) * 2;             // 0,2,...,14 (staged cols r0+cc, r0+cc+1)

    int gi0 = r0 + ii, gi1 = gi0 + 8, gj = c0 + jj;

    // ---- prologue ----
    {
        float2 v = *(const float2*)(xn + (c0 + jr) * M_ + r0 + cc);   // stage d=0
        *(float2*)&Bl[0][jr][cc] = v;
    }
    float2 sreg = *(const float2*)(xn + (size_t)1 * M_ * M_ + (c0 + jr) * M_ + r0 + cc); // stage d=1
    float dv0 = xn[gi0 * M_ + gj];    // direct d=0
    float dv1 = xn[gi1 * M_ + gj];
    float dv0n, dv1n;
    __syncthreads();                  // buf0 ready

    for (int d = 0; d < D_; ++d) {
        int nb = (d + 1) & 1;
        if (d + 1 < D_) {
            // write staged d+1 (loaded 1 iter ago); buf nb's readers passed last barrier
            *(float2*)&Bl[nb][jr][cc] = sreg;
            // prefetch direct d+1
            dv0n = xn[(size_t)(d + 1) * M_ * M_ + gi0 * M_ + gj];
            dv1n = xn[(size_t)(d + 1) * M_ * M_ + gi1 * M_ + gj];
        }
        if (d + 2 < D_) {
            // prefetch stage d+2 into regs
            sreg = *(const float2*)(xn + (size_t)(d + 2) * M_ * M_ + (c0 + jr) * M_ + r0 + cc);
        }
        float xt0 = Bl[d & 1][jj][ii];
        float xt1 = Bl[d & 1][jj][ii + 8];
        const float2* wd = wpack + d * S_;    // uniform -> s_load
#pragma unroll
        for (int s = 0; s < S_; ++s) {
            float2 cw = wd[s];
            acc0[s] = fmaf(cw.x, dv0, fmaf(cw.y, xt0, acc0[s]));
            acc1[s] = fmaf(cw.x, dv1, fmaf(cw.y, xt1, acc1[s]));
        }
        __syncthreads();              // ds_write(d+1) done; reads of buf[d&1] done
        dv0 = dv0n; dv1 = dv1n;
    }

    // epilogue: rank-1 terms + diagonal term + store
#pragma unroll
    for (int s = 0; s < S_; ++s) {
        int base = (n * S_ + s) * M_;
        float a0 = acc0[s] + Rv[base + gi0];
        float a1 = acc1[s] + Rv[base + gi1];
        float cvv = Cv[base + gj];
        a0 += cvv; a1 += cvv;
        if (gi0 == gj) a0 += Dg[base + gi0];
        if (gi1 == gj) a1 += Dg[base + gi1];
        out[(size_t)base * M_ + gi0 * M_ + gj] = a0;
        out[(size_t)base * M_ + gi1 * M_ + gj] = a1;
    }
}

extern "C" void kernel_launch(void* const* d_in, const int* in_sizes, int n_in,
                              void* d_out, int out_size, void* d_ws, size_t ws_size,
                              hipStream_t stream) {
    const float* x         = (const float*)d_in[0];
    const float* coefs     = (const float*)d_in[1];
    const float* bias      = (const float*)d_in[2];
    const float* diag_bias = (const float*)d_in[3];
    float* out = (float*)d_out;
    float* ws  = (float*)d_ws;   // needs ~3.1 MiB

    hipLaunchKernelGGL(eq2_reduce,  dim3(N_ * D_), dim3(256), 0, stream, x, ws);
    hipLaunchKernelGGL(eq2_combine, dim3(N_ * S_), dim3(128), 0, stream, coefs, bias, diag_bias, ws);
    hipLaunchKernelGGL(eq2_main,    dim3(1024), dim3(256), 0, stream, x, ws, out);
}